// Round 11
// baseline (370.027 us; speedup 1.0000x reference)
//
#include <hip/hip_runtime.h>

#define NORI 8
#define KS 7
#define CH 32
#define IMG 224
#define STRIP 32           // output rows per block
#define SROWS (STRIP + 6)  // staged input rows = 38
#define PITCH 232          // floats per staged row; col j holds x-col (j-4)

typedef float f4 __attribute__((ext_vector_type(4)));

// R9/R10 lesson: pin waves-per-eu so the RA budget (128 VGPR) matches the
// designed live set (~112) instead of squeezing to 64 and spilling.
__global__ void __attribute__((amdgpu_flat_work_group_size(256, 256),
                               amdgpu_waves_per_eu(4, 4)))
gabor_dw_conv(const float* __restrict__ x, const float* __restrict__ filt,
              float* __restrict__ out) {
    __shared__ __align__(16) float s_in[SROWS * PITCH];   // 35264 B

    // bijective XCD swizzle: nwg = 7*32*16 = 3584 = 8 * 448 exactly
    const int cpx = (7 * CH * 16) / 8;           // 448
    const int bid = blockIdx.x;
    const int logical = (bid & 7) * cpx + (bid >> 3);
    const int strip = logical % 7;
    const int plane = logical / 7;               // 0..511
    const int c = plane & (CH - 1);
    const int b = plane >> 5;
    const int gy0 = strip * STRIP;

    const int tid = threadIdx.x;
    const int wv  = tid >> 6;                    // wave 0..3 -> oris {2wv, 2wv+1}
    const int l   = tid & 63;

    // ---- stage input rows gy0-3 .. gy0+34 (coalesced 896B/row) ----
    const float* xp = x + (size_t)(b * CH + c) * (IMG * IMG);
    {
        const int gxw = l - 1;                   // float4 index in global row
        const bool xok = (gxw >= 0) && (gxw < IMG / 4);
        for (int row = wv; row < SROWS; row += 4) {
            int gy = gy0 - 3 + row;
            f4 v = (f4)0.f;
            if (xok && gy >= 0 && gy < IMG) v = *(const f4*)(xp + gy * IMG + 4 * gxw);
            if (l < 58) *(f4*)&s_in[row * PITCH + 4 * l] = v;
        }
    }

    // ---- 2 orientations' weights -> SGPRs (wave-uniform address) ----
    const int wb = __builtin_amdgcn_readfirstlane((c * NORI + 2 * wv) * 49);
    float w0[49], w1[49];
    #pragma unroll
    for (int k = 0; k < 49; ++k) { w0[k] = filt[wb + k]; w1[k] = filt[wb + 49 + k]; }

    __syncthreads();
    if (l >= 56) return;                         // 56 lanes x 4 px = 224

    float* op0 = out + ((size_t)(b * (CH * NORI) + c * NORI + 2 * wv) * IMG + gy0) * IMG + 4 * l;
    float* op1 = op0 + (size_t)IMG * IMG;

    // ring of 8 accumulators per ori; NO init (first tap ky==0,kx==0 overwrites;
    // slot m is stored at row i-2 and first re-touched at row i via ky=0)
    float a0[8][4], a1[8][4];
    float W[2][12];                              // 1-row-lookahead double buffer

#define RDW(BUF, R) do {                                                    \
    const f4* p_ = (const f4*)&s_in[(R) * PITCH + 4 * l];                   \
    f4 u0 = p_[0], u1 = p_[1], u2 = p_[2];                                  \
    W[BUF][0]=u0.x; W[BUF][1]=u0.y; W[BUF][2]=u0.z;  W[BUF][3]=u0.w;        \
    W[BUF][4]=u1.x; W[BUF][5]=u1.y; W[BUF][6]=u1.z;  W[BUF][7]=u1.w;        \
    W[BUF][8]=u2.x; W[BUF][9]=u2.y; W[BUF][10]=u2.z; W[BUF][11]=u2.w; } while (0)

#define TAPS(BUF, MM, KYMIN, KYMAX)                                         \
    _Pragma("unroll")                                                       \
    for (int ky = (KYMIN); ky <= (KYMAX); ++ky) {                           \
        const int s_ = ((MM) - ky) & 7;          /* static after unroll */  \
        _Pragma("unroll")                                                   \
        for (int kx = 0; kx < KS; ++kx) {                                   \
            const float c0_ = w0[ky * 7 + kx];   /* SGPR operands */        \
            const float c1_ = w1[ky * 7 + kx];                              \
            _Pragma("unroll")                                               \
            for (int p = 0; p < 4; ++p) {                                   \
                const float in_ = W[BUF][p + kx + 1];                       \
                if (ky == 0 && kx == 0) { a0[s_][p] = in_ * c0_;            \
                                          a1[s_][p] = in_ * c1_; }          \
                else                    { a0[s_][p] += in_ * c0_;           \
                                          a1[s_][p] += in_ * c1_; }         \
            }                                                               \
        }                                                                   \
    }

#define ST(MM, JR) do {                                                     \
    const int ss_ = ((MM) + 2) & 7;                                         \
    f4 v0_; v0_.x = a0[ss_][0]; v0_.y = a0[ss_][1];                         \
    v0_.z = a0[ss_][2]; v0_.w = a0[ss_][3];                                 \
    __builtin_nontemporal_store(v0_, (f4*)(op0 + (size_t)(JR) * IMG));      \
    f4 v1_; v1_.x = a1[ss_][0]; v1_.y = a1[ss_][1];                         \
    v1_.z = a1[ss_][2]; v1_.w = a1[ss_][3];                                 \
    __builtin_nontemporal_store(v1_, (f4*)(op1 + (size_t)(JR) * IMG));      \
    } while (0)

#define FENCE __builtin_amdgcn_sched_barrier(0)

    // prologue: rows 0..7; prefetch runs one row ahead (pipeline)
    RDW(0, 0);
    RDW(1, 1); TAPS(0, 0, 0, 0);
    RDW(0, 2); TAPS(1, 1, 0, 1); FENCE;
    RDW(1, 3); TAPS(0, 2, 0, 2);
    RDW(0, 4); TAPS(1, 3, 0, 3); FENCE;
    RDW(1, 5); TAPS(0, 4, 0, 4);
    RDW(0, 6); TAPS(1, 5, 0, 5); FENCE;
    RDW(1, 7); TAPS(0, 6, 0, 6); ST(6, 0);
    RDW(0, 8); TAPS(1, 7, 0, 6); ST(7, 1); FENCE;

    // steady: rows 8..31 in 8-row groups; entry invariant: W0 holds row i0
    #pragma clang loop unroll(disable)
    for (int g = 1; g <= 3; ++g) {
        const int i0 = 8 * g;
        RDW(1, i0 + 1); TAPS(0, 0, 0, 6); ST(0, i0 - 6);
        RDW(0, i0 + 2); TAPS(1, 1, 0, 6); ST(1, i0 - 5); FENCE;
        RDW(1, i0 + 3); TAPS(0, 2, 0, 6); ST(2, i0 - 4);
        RDW(0, i0 + 4); TAPS(1, 3, 0, 6); ST(3, i0 - 3); FENCE;
        RDW(1, i0 + 5); TAPS(0, 4, 0, 6); ST(4, i0 - 2);
        RDW(0, i0 + 6); TAPS(1, 5, 0, 6); ST(5, i0 - 1); FENCE;
        RDW(1, i0 + 7); TAPS(0, 6, 0, 6); ST(6, i0 + 0);
        RDW(0, i0 + 8); TAPS(1, 7, 0, 6); ST(7, i0 + 1); FENCE;
    }

    // epilogue: rows 32..37 (entry: W0 = row 32); stores j = 26..31
    RDW(1, 33); TAPS(0, 0, 1, 6); ST(0, 26);
    RDW(0, 34); TAPS(1, 1, 2, 6); ST(1, 27); FENCE;
    RDW(1, 35); TAPS(0, 2, 3, 6); ST(2, 28);
    RDW(0, 36); TAPS(1, 3, 4, 6); ST(3, 29); FENCE;
    RDW(1, 37); TAPS(0, 4, 5, 6); ST(4, 30);
                TAPS(1, 5, 6, 6); ST(5, 31);

#undef RDW
#undef TAPS
#undef ST
#undef FENCE
}

extern "C" void kernel_launch(void* const* d_in, const int* in_sizes, int n_in,
                              void* d_out, int out_size, void* d_ws, size_t ws_size,
                              hipStream_t stream) {
    const float* x = (const float*)d_in[0];
    const float* filt = (const float*)d_in[1];
    float* out = (float*)d_out;

    dim3 grid(7 * CH * 16);    // y-strips * channels * batch = 3584
    dim3 block(256);           // 4 waves; each wave computes 2 orientations
    gabor_dw_conv<<<grid, block, 0, stream>>>(x, filt, out);
}

// Round 12
// 199.576 us; speedup vs baseline: 1.8541x; 1.8541x over previous
//
#include <hip/hip_runtime.h>

#define NORI 8
#define KS 7
#define CH 32
#define IMG 224
#define STRIP 16
#define SROWS 23              // 16 out rows + 6 halo + 1 pad row (ky=7 zero-band reads)
#define PPR 232               // u32 pairs per LDS row: pair idx -4..227 at slot idx+4
#define PLANE (IMG * IMG)

typedef short s8 __attribute__((ext_vector_type(8)));      // bf16x8 MFMA frag
typedef float f16f __attribute__((ext_vector_type(16)));   // f32x16 acc
typedef float f4 __attribute__((ext_vector_type(4)));
typedef unsigned u32x4 __attribute__((ext_vector_type(4)));

__device__ inline unsigned f2bf(float f) {                 // RNE f32 -> bf16 bits
    unsigned u = __builtin_bit_cast(unsigned, f);
    return (u + 0x7FFFu + ((u >> 16) & 1u)) >> 16;
}

__global__ void __attribute__((amdgpu_flat_work_group_size(256, 256),
                               amdgpu_waves_per_eu(5, 5)))
gabor_mfma(const float* __restrict__ x, const float* __restrict__ filt,
           float* __restrict__ out) {
    __shared__ unsigned s_p[SROWS * PPR];    // 21344 B: overlapping bf16-pair tile

    // bijective XCD swizzle: nwg = 14*512 = 7168 = 8 * 896
    const int bid = blockIdx.x;
    const int logical = (bid & 7) * 896 + (bid >> 3);
    const int strip = logical % 14;
    const int plane = logical / 14;          // 0..511 = b*32 + ch
    const int ch = plane & (CH - 1);
    const int b  = plane >> 5;
    const int gy0 = strip * STRIP;

    const int tid = threadIdx.x;
    const int wv = tid >> 6;                 // wave 0..3
    const int l  = tid & 63;
    const int h  = l >> 5;                   // K-band half (0/1)
    const int n  = l & 31;                   // MFMA col / ori lane

    // ---- stage 23 rows as overlapping bf16 pairs: P[p] = (bf(x[p]), bf(x[p+1])) ----
    const float* xp = x + (size_t)(b * CH + ch) * PLANE;
    for (int r = wv; r < SROWS; r += 4) {
        const int gy = gy0 + r - 3;
        if (l < 58) {
            const int p0 = 4 * l - 4;        // this lane's first pair index
            f4 v = (f4)0.f;
            float e4 = 0.f;
            if (gy >= 0 && gy < IMG) {
                if (p0 >= 0 && p0 <= IMG - 4) v = *(const f4*)(xp + gy * IMG + p0);
                if (p0 + 4 <= IMG - 1)        e4 = xp[gy * IMG + p0 + 4];
            }
            unsigned c0 = f2bf(v.x), c1 = f2bf(v.y), c2 = f2bf(v.z),
                     c3 = f2bf(v.w), c4 = f2bf(e4);
            u32x4 pk;
            pk.x = c0 | (c1 << 16); pk.y = c1 | (c2 << 16);
            pk.z = c2 | (c3 << 16); pk.w = c3 | (c4 << 16);
            *(u32x4*)&s_p[r * PPR + 4 * l] = pk;   // slot = pair idx + 4, 16B aligned
        }
    }

    // ---- A-frags: weights, M-row = ori (l&31; >=8 zero), k = 8h + j -> ky=2q+h, kx=j ----
    s8 a0{}, a1{}, a2{}, a3{};
    {
        const float* fw = filt + (size_t)(ch * NORI) * 49;
#define MKA(AQ, Q)                                                          \
        { _Pragma("unroll")                                                 \
          for (int j = 0; j < 8; ++j) {                                     \
              const int ky = 2 * (Q) + h;                                   \
              float wval = (n < 8 && ky < 7 && j < 7)                       \
                               ? fw[n * 49 + ky * 7 + j] : 0.f;             \
              AQ[j] = (short)f2bf(wval);                                    \
          } }
        MKA(a0, 0) MKA(a1, 1) MKA(a2, 2) MKA(a3, 3)
#undef MKA
    }

    __syncthreads();

    // ---- compute: wave owns out rows yy = 4wv..4wv+3 as 2 chains {yy0, yy0+2} ----
    // B-frag (yy,q) rows = yy + 2q + h  ==  (yy+2, q-1): reuse 3 of 4 frags per chain.
    float* ob = out + (size_t)(plane * NORI + 4 * h) * PLANE + n;

#define RDB(BB, OFF)                                                        \
    { unsigned u0 = s_p[(OFF)], u1 = s_p[(OFF) + 2],                        \
               u2 = s_p[(OFF) + 4], u3 = s_p[(OFF) + 6];                    \
      u32x4 uu; uu.x = u0; uu.y = u1; uu.z = u2; uu.w = u3;                 \
      BB = __builtin_bit_cast(s8, uu); }

    for (int cc = 0; cc < 2; ++cc) {
        const int yy0 = 4 * wv + cc;
        const int Y0 = gy0 + yy0;
        for (int g = 0; g < 7; ++g) {
            const int x0 = 32 * g;
            // pair idx X = x0+n-3+2t -> u32 slot (yy0+h)*PPR + x0+n+1+2t
            const int vb = (yy0 + h) * PPR + x0 + n + 1;
            s8 b0, b1, b2, b3, b4;
            RDB(b0, vb);
            RDB(b1, vb + 2 * PPR);
            RDB(b2, vb + 4 * PPR);
            RDB(b3, vb + 6 * PPR);
            f16f acc0 = {};
            acc0 = __builtin_amdgcn_mfma_f32_32x32x16_bf16(a0, b0, acc0, 0, 0, 0);
            acc0 = __builtin_amdgcn_mfma_f32_32x32x16_bf16(a1, b1, acc0, 0, 0, 0);
            acc0 = __builtin_amdgcn_mfma_f32_32x32x16_bf16(a2, b2, acc0, 0, 0, 0);
            acc0 = __builtin_amdgcn_mfma_f32_32x32x16_bf16(a3, b3, acc0, 0, 0, 0);
            // D: col n = x0+n, rows (reg + 4h) = ori for reg 0..3; rest discarded
            ob[(size_t)0 * PLANE + (size_t)Y0 * IMG + x0] = acc0[0];
            ob[(size_t)1 * PLANE + (size_t)Y0 * IMG + x0] = acc0[1];
            ob[(size_t)2 * PLANE + (size_t)Y0 * IMG + x0] = acc0[2];
            ob[(size_t)3 * PLANE + (size_t)Y0 * IMG + x0] = acc0[3];

            RDB(b4, vb + 8 * PPR);           // new band for yy0+2
            f16f acc1 = {};
            acc1 = __builtin_amdgcn_mfma_f32_32x32x16_bf16(a0, b1, acc1, 0, 0, 0);
            acc1 = __builtin_amdgcn_mfma_f32_32x32x16_bf16(a1, b2, acc1, 0, 0, 0);
            acc1 = __builtin_amdgcn_mfma_f32_32x32x16_bf16(a2, b3, acc1, 0, 0, 0);
            acc1 = __builtin_amdgcn_mfma_f32_32x32x16_bf16(a3, b4, acc1, 0, 0, 0);
            ob[(size_t)0 * PLANE + (size_t)(Y0 + 2) * IMG + x0] = acc1[0];
            ob[(size_t)1 * PLANE + (size_t)(Y0 + 2) * IMG + x0] = acc1[1];
            ob[(size_t)2 * PLANE + (size_t)(Y0 + 2) * IMG + x0] = acc1[2];
            ob[(size_t)3 * PLANE + (size_t)(Y0 + 2) * IMG + x0] = acc1[3];
        }
    }
#undef RDB
}

extern "C" void kernel_launch(void* const* d_in, const int* in_sizes, int n_in,
                              void* d_out, int out_size, void* d_ws, size_t ws_size,
                              hipStream_t stream) {
    const float* x = (const float*)d_in[0];
    const float* filt = (const float*)d_in[1];
    float* out = (float*)d_out;

    dim3 grid(14 * CH * 16);   // 14 y-strips * 512 planes = 7168
    dim3 block(256);           // 4 waves; wave = 4 output rows, all 8 oris via MFMA
    gabor_mfma<<<grid, block, 0, stream>>>(x, filt, out);
}

// Round 13
// 154.665 us; speedup vs baseline: 2.3924x; 1.2904x over previous
//
#include <hip/hip_runtime.h>

#define NORI 8
#define KS 7
#define CH 32
#define IMG 224
#define STRIP 16
#define SROWS 23              // 16 out rows + 6 halo + 1 pad row (ky=7 zero-band reads)
#define PPR 232               // u32 pairs per LDS row: pair idx -4..227 at slot idx+4
#define PLANE (IMG * IMG)

typedef short s8 __attribute__((ext_vector_type(8)));      // bf16x8 MFMA frag
typedef float f16f __attribute__((ext_vector_type(16)));   // f32x16 acc
typedef float f4 __attribute__((ext_vector_type(4)));
typedef unsigned u32x4 __attribute__((ext_vector_type(4)));

__device__ inline unsigned f2bf(float f) {                 // RNE f32 -> bf16 bits
    unsigned u = __builtin_bit_cast(unsigned, f);
    return (u + 0x7FFFu + ((u >> 16) & 1u)) >> 16;
}

__global__ void __attribute__((amdgpu_flat_work_group_size(256, 256),
                               amdgpu_waves_per_eu(5, 5)))
gabor_mfma(const float* __restrict__ x, const float* __restrict__ filt,
           float* __restrict__ out) {
    __shared__ unsigned s_p[SROWS * PPR];    // 21344 B: overlapping bf16-pair tile

    // bijective XCD swizzle: nwg = 14*512 = 7168 = 8 * 896
    const int bid = blockIdx.x;
    const int logical = (bid & 7) * 896 + (bid >> 3);
    const int strip = logical % 14;
    const int plane = logical / 14;          // 0..511 = b*32 + ch
    const int ch = plane & (CH - 1);
    const int b  = plane >> 5;
    const int gy0 = strip * STRIP;

    const int tid = threadIdx.x;
    const int wv = tid >> 6;                 // wave 0..3
    const int l  = tid & 63;
    const int h  = l >> 5;                   // K-band half (0/1)
    const int n  = l & 31;                   // MFMA col / ori lane

    // ---- stage 23 rows as overlapping bf16 pairs: P[p] = (bf(x[p]), bf(x[p+1])) ----
    const float* xp = x + (size_t)(b * CH + ch) * PLANE;
    for (int r = wv; r < SROWS; r += 4) {
        const int gy = gy0 + r - 3;
        if (l < 58) {
            const int p0 = 4 * l - 4;        // this lane's first pair index
            f4 v = (f4)0.f;
            float e4 = 0.f;
            if (gy >= 0 && gy < IMG) {
                if (p0 >= 0 && p0 <= IMG - 4) v = *(const f4*)(xp + gy * IMG + p0);
                if (p0 + 4 <= IMG - 1)        e4 = xp[gy * IMG + p0 + 4];
            }
            unsigned c0 = f2bf(v.x), c1 = f2bf(v.y), c2 = f2bf(v.z),
                     c3 = f2bf(v.w), c4 = f2bf(e4);
            u32x4 pk;
            pk.x = c0 | (c1 << 16); pk.y = c1 | (c2 << 16);
            pk.z = c2 | (c3 << 16); pk.w = c3 | (c4 << 16);
            *(u32x4*)&s_p[r * PPR + 4 * l] = pk;   // slot = pair idx + 4, 16B aligned
        }
    }

    // ---- A-frags: weights, M-row = ori (l&31; >=8 zero), k = 8h + j -> ky=2q+h, kx=j ----
    s8 a0{}, a1{}, a2{}, a3{};
    {
        const float* fw = filt + (size_t)(ch * NORI) * 49;
#define MKA(AQ, Q)                                                          \
        { _Pragma("unroll")                                                 \
          for (int j = 0; j < 8; ++j) {                                     \
              const int ky = 2 * (Q) + h;                                   \
              float wval = (n < 8 && ky < 7 && j < 7)                       \
                               ? fw[n * 49 + ky * 7 + j] : 0.f;             \
              AQ[j] = (short)f2bf(wval);                                    \
          } }
        MKA(a0, 0) MKA(a1, 1) MKA(a2, 2) MKA(a3, 3)
#undef MKA
    }

    __syncthreads();

    // ---- compute: wave owns out rows yy = 4wv..4wv+3 as 2 chains {yy0, yy0+2} ----
    // B-frag (yy,q) rows = yy + 2q + h  ==  (yy+2, q-1): reuse 3 of 4 frags per chain.
    float* ob = out + (size_t)(plane * NORI + 4 * h) * PLANE + n;

#define RDB(BB, OFF)                                                        \
    { unsigned u0 = s_p[(OFF)], u1 = s_p[(OFF) + 2],                        \
               u2 = s_p[(OFF) + 4], u3 = s_p[(OFF) + 6];                    \
      u32x4 uu; uu.x = u0; uu.y = u1; uu.z = u2; uu.w = u3;                 \
      BB = __builtin_bit_cast(s8, uu); }

    for (int cc = 0; cc < 2; ++cc) {
        const int yy0 = 4 * wv + cc;
        const int Y0 = gy0 + yy0;
        for (int g = 0; g < 7; ++g) {
            const int x0 = 32 * g;
            // pair idx X = x0+n-3+2t -> u32 slot (yy0+h)*PPR + x0+n+1+2t
            const int vb = (yy0 + h) * PPR + x0 + n + 1;
            s8 b0, b1, b2, b3, b4;
            RDB(b0, vb);
            RDB(b1, vb + 2 * PPR);
            RDB(b2, vb + 4 * PPR);
            RDB(b3, vb + 6 * PPR);
            RDB(b4, vb + 8 * PPR);
            // two INDEPENDENT 4-MFMA chains, interleaved to halve exposed latency
            f16f acc0 = {}, acc1 = {};
            acc0 = __builtin_amdgcn_mfma_f32_32x32x16_bf16(a0, b0, acc0, 0, 0, 0);
            acc1 = __builtin_amdgcn_mfma_f32_32x32x16_bf16(a0, b1, acc1, 0, 0, 0);
            acc0 = __builtin_amdgcn_mfma_f32_32x32x16_bf16(a1, b1, acc0, 0, 0, 0);
            acc1 = __builtin_amdgcn_mfma_f32_32x32x16_bf16(a1, b2, acc1, 0, 0, 0);
            acc0 = __builtin_amdgcn_mfma_f32_32x32x16_bf16(a2, b2, acc0, 0, 0, 0);
            acc1 = __builtin_amdgcn_mfma_f32_32x32x16_bf16(a2, b3, acc1, 0, 0, 0);
            acc0 = __builtin_amdgcn_mfma_f32_32x32x16_bf16(a3, b3, acc0, 0, 0, 0);
            acc1 = __builtin_amdgcn_mfma_f32_32x32x16_bf16(a3, b4, acc1, 0, 0, 0);
            // D: col n = x0+n, rows (reg + 4h) = ori for reg 0..3; rest discarded.
            // Full 128-B lines (32 lanes x 4 B aligned), write-once -> nontemporal.
            __builtin_nontemporal_store(acc0[0], ob + (size_t)0 * PLANE + (size_t)Y0 * IMG + x0);
            __builtin_nontemporal_store(acc0[1], ob + (size_t)1 * PLANE + (size_t)Y0 * IMG + x0);
            __builtin_nontemporal_store(acc0[2], ob + (size_t)2 * PLANE + (size_t)Y0 * IMG + x0);
            __builtin_nontemporal_store(acc0[3], ob + (size_t)3 * PLANE + (size_t)Y0 * IMG + x0);
            __builtin_nontemporal_store(acc1[0], ob + (size_t)0 * PLANE + (size_t)(Y0 + 2) * IMG + x0);
            __builtin_nontemporal_store(acc1[1], ob + (size_t)1 * PLANE + (size_t)(Y0 + 2) * IMG + x0);
            __builtin_nontemporal_store(acc1[2], ob + (size_t)2 * PLANE + (size_t)(Y0 + 2) * IMG + x0);
            __builtin_nontemporal_store(acc1[3], ob + (size_t)3 * PLANE + (size_t)(Y0 + 2) * IMG + x0);
        }
    }
#undef RDB
}

extern "C" void kernel_launch(void* const* d_in, const int* in_sizes, int n_in,
                              void* d_out, int out_size, void* d_ws, size_t ws_size,
                              hipStream_t stream) {
    const float* x = (const float*)d_in[0];
    const float* filt = (const float*)d_in[1];
    float* out = (float*)d_out;

    dim3 grid(14 * CH * 16);   // 14 y-strips * 512 planes = 7168
    dim3 block(256);           // 4 waves; wave = 4 output rows, all 8 oris via MFMA
    gabor_mfma<<<grid, block, 0, stream>>>(x, filt, out);
}